// Round 1
// 280.832 us; speedup vs baseline: 1.0024x; 1.0024x over previous
//
#include <hip/hip_runtime.h>
#include <math.h>

// N nodes (50000), E edges (600000), D=128.
// Q = x@Wq.T; K = x@Wk.T; V = x@Wv.T  (node-level)
// per edge e=(s->d): c = sigmoid(dot(Q[d],K[s])/sqrt(128)); agg[d] += c*V[s]
// out = LN(x + agg@Wo.T + bo) * gamma + beta
//
// R2: f32 atomics hit TCC atomic ceiling -> counting-sort + per-node agg.
// R3: fp32 VALU GEMMs -> split-bf16 MFMA (C = xh*wh + xl*wh + xh*wl).
// R4: K/V bf16 (halved gather bytes, 25.6 MB working set).
// R5: node_agg KV-interleaved (1 dwordx2/edge/lane), ds_swizzle reduce,
//     masked full-width batches.
// R6: single-block scan was a 103 us latency chain (1 CU, dependent loads)
//     -> revert to multi-block 3-kernel scan (R4-proven, few us each).
// R7: node_agg was VALU-issue-bound (95% VALUBusy, 0% Mfma, 39% HBM).
//     -> sublane layout: 16 lanes x 8 elem per edge; 4 edges share one
//        wave, one 4-step swizzle reduce serves 4 edges at once;
//        sigmoid via v_rcp (precise div was ~8 VALU/edge);
//        Q pre-scaled by -1/sqrt(128) in qkv_mfma epilogue.

#define BM 64
#define QSCALE -0.08838834764831845f   /* -1/sqrt(128), folded into Q */

typedef __attribute__((ext_vector_type(8))) short bfrag;   // 8 bf16 = 4 VGPRs
typedef __attribute__((ext_vector_type(4))) float f32x4;

__device__ __forceinline__ short f2bf(float f) {
    union { float f; unsigned u; } v; v.f = f;
    unsigned r = v.u + 0x7FFFu + ((v.u >> 16) & 1u);   // round-to-nearest-even
    return (short)(r >> 16);
}
__device__ __forceinline__ float bf2f(short h) {
    union { unsigned u; float f; } v;
    v.u = ((unsigned)(unsigned short)h) << 16;
    return v.f;
}
// dword holds (K at low ushort, V at high ushort)
__device__ __forceinline__ float klo(unsigned w) {
    union { unsigned u; float f; } v; v.u = w << 16; return v.f;
}
__device__ __forceinline__ float vhi(unsigned w) {
    union { unsigned u; float f; } v; v.u = w & 0xffff0000u; return v.f;
}

#define SWZ(x, pat) __int_as_float(__builtin_amdgcn_ds_swizzle(__float_as_int(x), pat))

// ---------- fused: zero hist (N ints) + weight split fp32->bf16 hi/lo ----
__global__ __launch_bounds__(256) void zero_prep(
    const float* __restrict__ Wq, const float* __restrict__ Wk,
    const float* __restrict__ Wv, const float* __restrict__ Wo,
    short* __restrict__ whi, short* __restrict__ wlo,
    int* __restrict__ hist, int N)
{
    int g = blockIdx.x * 256 + threadIdx.x;
    if (g < N) hist[g] = 0;
    if (g < 65536) {
        const float* Ws[4] = {Wq, Wk, Wv, Wo};
        float f = Ws[g >> 14][g & 16383];
        short h = f2bf(f);
        short l = f2bf(f - bf2f(h));
        whi[g] = h; wlo[g] = l;
    }
}

// ---------------- fused QKV projection via split-bf16 MFMA ----------------
// Q written fp32 (pre-scaled by -1/sqrt(128)); K,V written element-interleaved
// bf16: KV16[node*256 + 2*i] = K[node][i], KV16[node*256 + 2*i + 1] = V[node][i]
__global__ __launch_bounds__(256) void qkv_mfma(
    const float* __restrict__ x,
    const short* __restrict__ whi, const short* __restrict__ wlo,
    float* __restrict__ Q, unsigned short* __restrict__ KV16, int N)
{
    __shared__ short xs_hi[64][136];   // +8 pad: row 272 B -> 2-way LDS (free)
    __shared__ short xs_lo[64][136];

    const int tid = threadIdx.x;
    const int row0 = blockIdx.x * BM;

    #pragma unroll
    for (int i = 0; i < 8; ++i) {
        int idx = tid + 256 * i;
        int r = idx >> 5;
        int c4 = idx & 31;
        int gr = row0 + r;
        float4 val = make_float4(0.f, 0.f, 0.f, 0.f);
        if (gr < N) val = ((const float4*)(x + (size_t)gr * 128))[c4];
        short4 h, l;
        h.x = f2bf(val.x); l.x = f2bf(val.x - bf2f(h.x));
        h.y = f2bf(val.y); l.y = f2bf(val.y - bf2f(h.y));
        h.z = f2bf(val.z); l.z = f2bf(val.z - bf2f(h.z));
        h.w = f2bf(val.w); l.w = f2bf(val.w - bf2f(h.w));
        *((short4*)&xs_hi[r][c4 * 4]) = h;
        *((short4*)&xs_lo[r][c4 * 4]) = l;
    }
    __syncthreads();

    const int wid  = tid >> 6;
    const int lane = tid & 63;
    const int n16  = lane & 15;
    const int quad = lane >> 4;

    #pragma unroll 1
    for (int mat = 0; mat < 3; ++mat) {
        const short* __restrict__ WH = whi + mat * 16384;
        const short* __restrict__ WL = wlo + mat * 16384;
        const f32x4 zero = {0.f, 0.f, 0.f, 0.f};
        f32x4 acc[4][2];
        #pragma unroll
        for (int t = 0; t < 4; ++t) { acc[t][0] = zero; acc[t][1] = zero; }

        #pragma unroll
        for (int kc = 0; kc < 4; ++kc) {
            int k0 = kc * 32 + quad * 8;
            bfrag ah[4], al[4], bh[2], bl[2];
            #pragma unroll
            for (int t = 0; t < 4; ++t) {
                ah[t] = *((const bfrag*)&xs_hi[t * 16 + n16][k0]);
                al[t] = *((const bfrag*)&xs_lo[t * 16 + n16][k0]);
            }
            #pragma unroll
            for (int c = 0; c < 2; ++c) {
                int wr = (wid * 2 + c) * 16 + n16;
                bh[c] = *((const bfrag*)(WH + wr * 128 + k0));
                bl[c] = *((const bfrag*)(WL + wr * 128 + k0));
            }
            #pragma unroll
            for (int t = 0; t < 4; ++t)
                #pragma unroll
                for (int c = 0; c < 2; ++c) {
                    acc[t][c] = __builtin_amdgcn_mfma_f32_16x16x32_bf16(ah[t], bh[c], acc[t][c], 0, 0, 0);
                    acc[t][c] = __builtin_amdgcn_mfma_f32_16x16x32_bf16(al[t], bh[c], acc[t][c], 0, 0, 0);
                    acc[t][c] = __builtin_amdgcn_mfma_f32_16x16x32_bf16(ah[t], bl[c], acc[t][c], 0, 0, 0);
                }
        }
        #pragma unroll
        for (int t = 0; t < 4; ++t)
            #pragma unroll
            for (int r = 0; r < 4; ++r) {
                int grow = row0 + t * 16 + quad * 4 + r;
                if (grow < N) {
                    int c0 = (wid * 2 + 0) * 16 + n16;
                    int c1 = (wid * 2 + 1) * 16 + n16;
                    if (mat == 0) {
                        Q[(size_t)grow * 128 + c0] = acc[t][0][r] * QSCALE;
                        Q[(size_t)grow * 128 + c1] = acc[t][1][r] * QSCALE;
                    } else {
                        size_t base = (size_t)grow * 256 + (mat - 1);  // K at +0, V at +1
                        KV16[base + 2 * c0] = (unsigned short)f2bf(acc[t][0][r]);
                        KV16[base + 2 * c1] = (unsigned short)f2bf(acc[t][1][r]);
                    }
                }
            }
    }
}

// ---------------- counting sort of edges by dst ----------------
__global__ __launch_bounds__(256) void hist_kernel(
    const int* __restrict__ ei, int* __restrict__ hist, int E)
{
    int e = blockIdx.x * blockDim.x + threadIdx.x;
    if (e < E) atomicAdd(&hist[ei[E + e]], 1);
}

#define SCAN_TPB 256
#define SCAN_EPT 4   // 1024 elements per scan block

__global__ __launch_bounds__(SCAN_TPB) void scan_partial(
    const int* __restrict__ hist, int* __restrict__ offs,
    int* __restrict__ blockSums, int N)
{
    __shared__ int sdata[SCAN_TPB];
    int b = blockIdx.x;
    int t = threadIdx.x;
    int base = b * SCAN_TPB * SCAN_EPT + t * SCAN_EPT;
    int v[SCAN_EPT];
    int tot = 0;
    #pragma unroll
    for (int j = 0; j < SCAN_EPT; ++j) {
        int idx = base + j;
        v[j] = (idx < N) ? hist[idx] : 0;
        tot += v[j];
    }
    sdata[t] = tot;
    __syncthreads();
    for (int off = 1; off < SCAN_TPB; off <<= 1) {
        int xv = (t >= off) ? sdata[t - off] : 0;
        __syncthreads();
        sdata[t] += xv;
        __syncthreads();
    }
    int run = sdata[t] - tot;
    #pragma unroll
    for (int j = 0; j < SCAN_EPT; ++j) {
        int idx = base + j;
        if (idx < N) offs[idx] = run;
        run += v[j];
    }
    if (t == SCAN_TPB - 1) blockSums[b] = sdata[t];
}

__global__ __launch_bounds__(256) void scan_blocksums(int* __restrict__ blockSums, int nb)
{
    __shared__ int sdata[256];
    int t = threadIdx.x;
    int orig = (t < nb) ? blockSums[t] : 0;
    sdata[t] = orig;
    __syncthreads();
    for (int off = 1; off < 256; off <<= 1) {
        int xv = (t >= off) ? sdata[t - off] : 0;
        __syncthreads();
        sdata[t] += xv;
        __syncthreads();
    }
    if (t < nb) blockSums[t] = sdata[t] - orig;
}

// adds block prefix; writes both offs (scatter working copy) and starts (kept)
__global__ __launch_bounds__(256) void scan_add(
    int* __restrict__ offs, int* __restrict__ starts,
    const int* __restrict__ blockSums, int N)
{
    int idx = blockIdx.x * blockDim.x + threadIdx.x;
    if (idx < N) {
        int vv = offs[idx] + blockSums[idx >> 10];
        offs[idx] = vv;
        starts[idx] = vv;
    }
}

// scatter: offs[d] consumed (becomes END offset after all increments)
__global__ __launch_bounds__(256) void scatter_kernel(
    const int* __restrict__ ei, int* __restrict__ offs,
    int* __restrict__ ssrc, int E)
{
    int e = blockIdx.x * blockDim.x + threadIdx.x;
    if (e < E) {
        int d = ei[E + e];
        int pos = atomicAdd(&offs[d], 1);
        ssrc[pos] = ei[e];
    }
}

// ---------------- per-node attention aggregation (no atomics) ----------------
// R7 layout: one wave per dst node; 4 edge slots (lane>>4) x 16 sublanes
// (lane&15) x 8 elements each. One 4-step swizzle allreduce (xor 1,2,4,8,
// all within a 32-lane half) reduces FOUR edges' dot products at once.
// 2 edges per slot per iteration (8 edges/iter) keep loads pipelined.
// Q is pre-scaled by -1/sqrt(128); sigmoid = v_rcp(1 + v_exp(p)).
__global__ __launch_bounds__(256) void node_agg(
    const int* __restrict__ ssrc,
    const int* __restrict__ starts,
    const int* __restrict__ endoffs,
    const float* __restrict__ Q, const unsigned short* __restrict__ KV16,
    float* __restrict__ agg, int N)
{
    int node = blockIdx.x * 4 + (threadIdx.x >> 6);
    if (node >= N) return;
    int lane = threadIdx.x & 63;
    int eg   = lane >> 4;        // edge slot 0..3
    int sl   = lane & 15;        // element group: elements sl*8 .. sl*8+7
    int start = starts[node];
    int end   = endoffs[node];

    const float4 q0 = *((const float4*)(Q + (size_t)node * 128 + sl * 8));
    const float4 q1 = *((const float4*)(Q + (size_t)node * 128 + sl * 8 + 4));

    float a0 = 0.f, a1 = 0.f, a2 = 0.f, a3 = 0.f;
    float a4 = 0.f, a5 = 0.f, a6 = 0.f, a7 = 0.f;

    const unsigned short* kvbase = KV16 + sl * 16;   // + s*256 per edge

    for (int i = start; i < end; i += 8) {
        int i0 = i + eg;
        int i1 = i + 4 + eg;
        int ok0 = (i0 < end);
        int ok1 = (i1 < end);
        i0 = ok0 ? i0 : (end - 1);
        i1 = ok1 ? i1 : (end - 1);
        int s0 = ssrc[i0];
        int s1 = ssrc[i1];
        const unsigned short* kp0 = kvbase + ((size_t)s0 << 8);
        const unsigned short* kp1 = kvbase + ((size_t)s1 << 8);
        uint4 wa0 = *((const uint4*)kp0);
        uint4 wa1 = *((const uint4*)(kp0 + 8));
        uint4 wb0 = *((const uint4*)kp1);
        uint4 wb1 = *((const uint4*)(kp1 + 8));

        // dot products (K in low ushort of each dword)
        float p0, p1;
        p0 = q0.x * klo(wa0.x);
        p0 = fmaf(q0.y, klo(wa0.y), p0);
        p0 = fmaf(q0.z, klo(wa0.z), p0);
        p0 = fmaf(q0.w, klo(wa0.w), p0);
        p0 = fmaf(q1.x, klo(wa1.x), p0);
        p0 = fmaf(q1.y, klo(wa1.y), p0);
        p0 = fmaf(q1.z, klo(wa1.z), p0);
        p0 = fmaf(q1.w, klo(wa1.w), p0);
        p1 = q0.x * klo(wb0.x);
        p1 = fmaf(q0.y, klo(wb0.y), p1);
        p1 = fmaf(q0.z, klo(wb0.z), p1);
        p1 = fmaf(q0.w, klo(wb0.w), p1);
        p1 = fmaf(q1.x, klo(wb1.x), p1);
        p1 = fmaf(q1.y, klo(wb1.y), p1);
        p1 = fmaf(q1.z, klo(wb1.z), p1);
        p1 = fmaf(q1.w, klo(wb1.w), p1);

        // 4-step allreduce within each 16-lane group (serves 4 edges at once)
        p0 += SWZ(p0, 0x041F); p1 += SWZ(p1, 0x041F);
        p0 += SWZ(p0, 0x081F); p1 += SWZ(p1, 0x081F);
        p0 += SWZ(p0, 0x101F); p1 += SWZ(p1, 0x101F);
        p0 += SWZ(p0, 0x201F); p1 += SWZ(p1, 0x201F);

        // sigmoid(q.k/sqrt(D)): Q pre-scaled negative -> c = 1/(1+exp(p))
        float c0 = __builtin_amdgcn_rcpf(1.f + __expf(p0));
        float c1 = __builtin_amdgcn_rcpf(1.f + __expf(p1));
        if (!ok0) c0 = 0.f;
        if (!ok1) c1 = 0.f;

        // accumulate c*V (V in high ushort of each dword)
        a0 = fmaf(c0, vhi(wa0.x), a0); a0 = fmaf(c1, vhi(wb0.x), a0);
        a1 = fmaf(c0, vhi(wa0.y), a1); a1 = fmaf(c1, vhi(wb0.y), a1);
        a2 = fmaf(c0, vhi(wa0.z), a2); a2 = fmaf(c1, vhi(wb0.z), a2);
        a3 = fmaf(c0, vhi(wa0.w), a3); a3 = fmaf(c1, vhi(wb0.w), a3);
        a4 = fmaf(c0, vhi(wa1.x), a4); a4 = fmaf(c1, vhi(wb1.x), a4);
        a5 = fmaf(c0, vhi(wa1.y), a5); a5 = fmaf(c1, vhi(wb1.y), a5);
        a6 = fmaf(c0, vhi(wa1.z), a6); a6 = fmaf(c1, vhi(wb1.z), a6);
        a7 = fmaf(c0, vhi(wa1.w), a7); a7 = fmaf(c1, vhi(wb1.w), a7);
    }

    // combine the 4 edge-slot groups: xor16 (swizzle) + xor32 (shfl)
    a0 += SWZ(a0, 0x401F); a1 += SWZ(a1, 0x401F);
    a2 += SWZ(a2, 0x401F); a3 += SWZ(a3, 0x401F);
    a4 += SWZ(a4, 0x401F); a5 += SWZ(a5, 0x401F);
    a6 += SWZ(a6, 0x401F); a7 += SWZ(a7, 0x401F);
    a0 += __shfl_xor(a0, 32); a1 += __shfl_xor(a1, 32);
    a2 += __shfl_xor(a2, 32); a3 += __shfl_xor(a3, 32);
    a4 += __shfl_xor(a4, 32); a5 += __shfl_xor(a5, 32);
    a6 += __shfl_xor(a6, 32); a7 += __shfl_xor(a7, 32);

    if (eg == 0) {
        *((float4*)(agg + (size_t)node * 128 + sl * 8))     = make_float4(a0, a1, a2, a3);
        *((float4*)(agg + (size_t)node * 128 + sl * 8 + 4)) = make_float4(a4, a5, a6, a7);
    }
}

// ------- output GEMM (split-bf16 MFMA) + bias + residual + LayerNorm -------
__global__ __launch_bounds__(256) void out_ln_mfma(
    const float* __restrict__ agg,
    const short* __restrict__ whi, const short* __restrict__ wlo,  // Wo = mat 3
    const float* __restrict__ bo, const float* __restrict__ x,
    const float* __restrict__ gamma, const float* __restrict__ beta,
    float* __restrict__ out, int N)
{
    __shared__ __align__(16) char smem[64 * 136 * 2 * 2];   // 69632 B
    short (*xs_hi)[136] = (short(*)[136])smem;
    short (*xs_lo)[136] = (short(*)[136])(smem + 64 * 136 * 2);
    float (*hs)[132]    = (float(*)[132])smem;               // reused post-GEMM

    const int tid = threadIdx.x;
    const int row0 = blockIdx.x * BM;

    #pragma unroll
    for (int i = 0; i < 8; ++i) {
        int idx = tid + 256 * i;
        int r = idx >> 5;
        int c4 = idx & 31;
        int gr = row0 + r;
        float4 val = make_float4(0.f, 0.f, 0.f, 0.f);
        if (gr < N) val = ((const float4*)(agg + (size_t)gr * 128))[c4];
        short4 h, l;
        h.x = f2bf(val.x); l.x = f2bf(val.x - bf2f(h.x));
        h.y = f2bf(val.y); l.y = f2bf(val.y - bf2f(h.y));
        h.z = f2bf(val.z); l.z = f2bf(val.z - bf2f(h.z));
        h.w = f2bf(val.w); l.w = f2bf(val.w - bf2f(h.w));
        *((short4*)&xs_hi[r][c4 * 4]) = h;
        *((short4*)&xs_lo[r][c4 * 4]) = l;
    }
    __syncthreads();

    const int wid  = tid >> 6;
    const int lane = tid & 63;
    const int n16  = lane & 15;
    const int quad = lane >> 4;
    const short* __restrict__ WH = whi + 3 * 16384;
    const short* __restrict__ WL = wlo + 3 * 16384;

    const f32x4 zero = {0.f, 0.f, 0.f, 0.f};
    f32x4 acc[4][2];
    #pragma unroll
    for (int t = 0; t < 4; ++t) { acc[t][0] = zero; acc[t][1] = zero; }

    #pragma unroll
    for (int kc = 0; kc < 4; ++kc) {
        int k0 = kc * 32 + quad * 8;
        bfrag ah[4], al[4], bh[2], bl[2];
        #pragma unroll
        for (int t = 0; t < 4; ++t) {
            ah[t] = *((const bfrag*)&xs_hi[t * 16 + n16][k0]);
            al[t] = *((const bfrag*)&xs_lo[t * 16 + n16][k0]);
        }
        #pragma unroll
        for (int c = 0; c < 2; ++c) {
            int wr = (wid * 2 + c) * 16 + n16;
            bh[c] = *((const bfrag*)(WH + wr * 128 + k0));
            bl[c] = *((const bfrag*)(WL + wr * 128 + k0));
        }
        #pragma unroll
        for (int t = 0; t < 4; ++t)
            #pragma unroll
            for (int c = 0; c < 2; ++c) {
                acc[t][c] = __builtin_amdgcn_mfma_f32_16x16x32_bf16(ah[t], bh[c], acc[t][c], 0, 0, 0);
                acc[t][c] = __builtin_amdgcn_mfma_f32_16x16x32_bf16(al[t], bh[c], acc[t][c], 0, 0, 0);
                acc[t][c] = __builtin_amdgcn_mfma_f32_16x16x32_bf16(ah[t], bl[c], acc[t][c], 0, 0, 0);
            }
    }
    __syncthreads();   // all xs reads done before hs overwrite

    #pragma unroll
    for (int t = 0; t < 4; ++t)
        #pragma unroll
        for (int r = 0; r < 4; ++r) {
            hs[t * 16 + quad * 4 + r][(wid * 2 + 0) * 16 + n16] = acc[t][0][r];
            hs[t * 16 + quad * 4 + r][(wid * 2 + 1) * 16 + n16] = acc[t][1][r];
        }
    __syncthreads();

    {
        int r = tid >> 2;
        int qd = tid & 3;
        int gr = row0 + r;
        float sum = 0.f, sq = 0.f;
        #pragma unroll
        for (int c = 0; c < 32; c += 4) {
            float4 g4 = *((float4*)&hs[r][qd * 32 + c]);
            float4 b4 = *((const float4*)(bo + qd * 32 + c));
            float4 x4 = make_float4(0.f, 0.f, 0.f, 0.f);
            if (gr < N) x4 = *((const float4*)(x + (size_t)gr * 128 + qd * 32 + c));
            float4 h = make_float4(g4.x + b4.x + x4.x, g4.y + b4.y + x4.y,
                                   g4.z + b4.z + x4.z, g4.w + b4.w + x4.w);
            *((float4*)&hs[r][qd * 32 + c]) = h;
            sum += h.x + h.y + h.z + h.w;
            sq += h.x * h.x + h.y * h.y + h.z * h.z + h.w * h.w;
        }
        sum += __shfl_xor(sum, 1); sum += __shfl_xor(sum, 2);
        sq  += __shfl_xor(sq, 1);  sq  += __shfl_xor(sq, 2);
        float mu = sum * (1.f / 128.f);
        float var = sq * (1.f / 128.f) - mu * mu;
        float rs = rsqrtf(var + 1e-5f);
        if (gr < N) {
            #pragma unroll
            for (int c = 0; c < 32; c += 4) {
                float4 h = *((float4*)&hs[r][qd * 32 + c]);
                float4 g = *((const float4*)(gamma + qd * 32 + c));
                float4 b = *((const float4*)(beta + qd * 32 + c));
                float4 o = make_float4((h.x - mu) * rs * g.x + b.x,
                                       (h.y - mu) * rs * g.y + b.y,
                                       (h.z - mu) * rs * g.z + b.z,
                                       (h.w - mu) * rs * g.w + b.w);
                *((float4*)(out + (size_t)gr * 128 + qd * 32 + c)) = o;
            }
        }
    }
}

extern "C" void kernel_launch(void* const* d_in, const int* in_sizes, int n_in,
                              void* d_out, int out_size, void* d_ws, size_t ws_size,
                              hipStream_t stream) {
    const float* x     = (const float*)d_in[0];
    const int*   ei    = (const int*)d_in[1];
    const float* Wq    = (const float*)d_in[2];
    const float* Wk    = (const float*)d_in[3];
    const float* Wv    = (const float*)d_in[4];
    const float* Wo    = (const float*)d_in[5];
    const float* bo    = (const float*)d_in[6];
    const float* gamma = (const float*)d_in[7];
    const float* beta  = (const float*)d_in[8];
    const int N = in_sizes[0] / 128;
    const int E = in_sizes[1] / 2;
    const size_t ND = (size_t)N * 128;

    // workspace: Q fp32 25.6MB + KV16 interleaved bf16 25.6MB + agg 25.6MB
    //            + hist/offs/starts + blockSums + ssrc + whi/wlo
    float* ws  = (float*)d_ws;
    float* Q   = ws;
    unsigned short* KV16 = (unsigned short*)(Q + ND);    // 2*ND ushorts
    float* agg = (float*)(KV16 + 2 * ND);
    int* hist      = (int*)(agg + ND);
    int* offs      = hist + N;
    int* starts    = offs + N;
    int* blockSums = starts + N;       // 256 ints
    int* ssrc      = blockSums + 256;  // E ints
    short* whi     = (short*)(ssrc + E);        // 4*16384 shorts
    short* wlo     = whi + 4 * 16384;

    const int gzp = ((N > 65536 ? N : 65536) + 255) / 256;
    zero_prep<<<gzp, 256, 0, stream>>>(Wq, Wk, Wv, Wo, whi, wlo, hist, N);

    hist_kernel<<<(E + 255) / 256, 256, 0, stream>>>(ei, hist, E);
    const int nScanBlocks = (N + SCAN_TPB * SCAN_EPT - 1) / (SCAN_TPB * SCAN_EPT);
    scan_partial<<<nScanBlocks, SCAN_TPB, 0, stream>>>(hist, offs, blockSums, N);
    scan_blocksums<<<1, 256, 0, stream>>>(blockSums, nScanBlocks);
    scan_add<<<(N + 255) / 256, 256, 0, stream>>>(offs, starts, blockSums, N);
    scatter_kernel<<<(E + 255) / 256, 256, 0, stream>>>(ei, offs, ssrc, E);

    const int gq = (N + BM - 1) / BM;
    qkv_mfma<<<gq, 256, 0, stream>>>(x, whi, wlo, Q, KV16, N);

    node_agg<<<(N + 3) / 4, 256, 0, stream>>>(ssrc, starts, offs, Q, KV16, agg, N);

    out_ln_mfma<<<gq, 256, 0, stream>>>(agg, whi, wlo, bo, x, gamma, beta,
                                        (float*)d_out, N);
}

// Round 2
// 268.166 us; speedup vs baseline: 1.0498x; 1.0472x over previous
//
#include <hip/hip_runtime.h>
#include <math.h>

// N nodes (50000), E edges (600000), D=128.
// Q = x@Wq.T; K = x@Wk.T; V = x@Wv.T  (node-level)
// per edge e=(s->d): c = sigmoid(dot(Q[d],K[s])/sqrt(128)); agg[d] += c*V[s]
// out = LN(x + agg@Wo.T + bo) * gamma + beta
//
// R2: f32 atomics hit TCC atomic ceiling -> counting-sort + per-node agg.
// R3: fp32 VALU GEMMs -> split-bf16 MFMA (C = xh*wh + xl*wh + xh*wl).
// R4: K/V bf16 (halved gather bytes, 25.6 MB working set).
// R5: node_agg KV-interleaved (1 dwordx2/edge/lane), ds_swizzle reduce,
//     masked full-width batches.
// R6: single-block scan was a 103 us latency chain -> multi-block scan.
// R7: node_agg VALU-issue-bound -> 16-lane-per-edge sublane layout, one
//     swizzle reduce serves 4 edges, v_rcp sigmoid, Q pre-scaled.
// R8: R7 left node_agg gather-latency-bound (VALU 38%, HBM 48%, occ 63%).
//     -> 1-deep software pipeline (prefetch next batch ssrc+KV before
//        computing current; wave-uniform guard avoids phantom traffic);
//        Q stored bf16 (halves Q bytes both sides);
//        scan_blocksums folded into scan_add (one fewer launch).

#define BM 64
#define QSCALE -0.08838834764831845f   /* -1/sqrt(128), folded into Q */

typedef __attribute__((ext_vector_type(8))) short bfrag;   // 8 bf16 = 4 VGPRs
typedef __attribute__((ext_vector_type(4))) float f32x4;

__device__ __forceinline__ short f2bf(float f) {
    union { float f; unsigned u; } v; v.f = f;
    unsigned r = v.u + 0x7FFFu + ((v.u >> 16) & 1u);   // round-to-nearest-even
    return (short)(r >> 16);
}
__device__ __forceinline__ float bf2f(short h) {
    union { unsigned u; float f; } v;
    v.u = ((unsigned)(unsigned short)h) << 16;
    return v.f;
}
// dword holds (K at low ushort, V at high ushort)
__device__ __forceinline__ float klo(unsigned w) {
    union { unsigned u; float f; } v; v.u = w << 16; return v.f;
}
__device__ __forceinline__ float vhi(unsigned w) {
    union { unsigned u; float f; } v; v.u = w & 0xffff0000u; return v.f;
}

#define SWZ(x, pat) __int_as_float(__builtin_amdgcn_ds_swizzle(__float_as_int(x), pat))

// ---------- fused: zero hist (N ints) + weight split fp32->bf16 hi/lo ----
__global__ __launch_bounds__(256) void zero_prep(
    const float* __restrict__ Wq, const float* __restrict__ Wk,
    const float* __restrict__ Wv, const float* __restrict__ Wo,
    short* __restrict__ whi, short* __restrict__ wlo,
    int* __restrict__ hist, int N)
{
    int g = blockIdx.x * 256 + threadIdx.x;
    if (g < N) hist[g] = 0;
    if (g < 65536) {
        const float* Ws[4] = {Wq, Wk, Wv, Wo};
        float f = Ws[g >> 14][g & 16383];
        short h = f2bf(f);
        short l = f2bf(f - bf2f(h));
        whi[g] = h; wlo[g] = l;
    }
}

// ---------------- fused QKV projection via split-bf16 MFMA ----------------
// Q written bf16 pre-scaled by -1/sqrt(128); K,V element-interleaved bf16:
// KV16[node*256 + 2*i] = K[node][i], KV16[node*256 + 2*i + 1] = V[node][i]
__global__ __launch_bounds__(256) void qkv_mfma(
    const float* __restrict__ x,
    const short* __restrict__ whi, const short* __restrict__ wlo,
    unsigned short* __restrict__ Q16, unsigned short* __restrict__ KV16, int N)
{
    __shared__ short xs_hi[64][136];   // +8 pad: row 272 B -> 2-way LDS (free)
    __shared__ short xs_lo[64][136];

    const int tid = threadIdx.x;
    const int row0 = blockIdx.x * BM;

    #pragma unroll
    for (int i = 0; i < 8; ++i) {
        int idx = tid + 256 * i;
        int r = idx >> 5;
        int c4 = idx & 31;
        int gr = row0 + r;
        float4 val = make_float4(0.f, 0.f, 0.f, 0.f);
        if (gr < N) val = ((const float4*)(x + (size_t)gr * 128))[c4];
        short4 h, l;
        h.x = f2bf(val.x); l.x = f2bf(val.x - bf2f(h.x));
        h.y = f2bf(val.y); l.y = f2bf(val.y - bf2f(h.y));
        h.z = f2bf(val.z); l.z = f2bf(val.z - bf2f(h.z));
        h.w = f2bf(val.w); l.w = f2bf(val.w - bf2f(h.w));
        *((short4*)&xs_hi[r][c4 * 4]) = h;
        *((short4*)&xs_lo[r][c4 * 4]) = l;
    }
    __syncthreads();

    const int wid  = tid >> 6;
    const int lane = tid & 63;
    const int n16  = lane & 15;
    const int quad = lane >> 4;

    #pragma unroll 1
    for (int mat = 0; mat < 3; ++mat) {
        const short* __restrict__ WH = whi + mat * 16384;
        const short* __restrict__ WL = wlo + mat * 16384;
        const f32x4 zero = {0.f, 0.f, 0.f, 0.f};
        f32x4 acc[4][2];
        #pragma unroll
        for (int t = 0; t < 4; ++t) { acc[t][0] = zero; acc[t][1] = zero; }

        #pragma unroll
        for (int kc = 0; kc < 4; ++kc) {
            int k0 = kc * 32 + quad * 8;
            bfrag ah[4], al[4], bh[2], bl[2];
            #pragma unroll
            for (int t = 0; t < 4; ++t) {
                ah[t] = *((const bfrag*)&xs_hi[t * 16 + n16][k0]);
                al[t] = *((const bfrag*)&xs_lo[t * 16 + n16][k0]);
            }
            #pragma unroll
            for (int c = 0; c < 2; ++c) {
                int wr = (wid * 2 + c) * 16 + n16;
                bh[c] = *((const bfrag*)(WH + wr * 128 + k0));
                bl[c] = *((const bfrag*)(WL + wr * 128 + k0));
            }
            #pragma unroll
            for (int t = 0; t < 4; ++t)
                #pragma unroll
                for (int c = 0; c < 2; ++c) {
                    acc[t][c] = __builtin_amdgcn_mfma_f32_16x16x32_bf16(ah[t], bh[c], acc[t][c], 0, 0, 0);
                    acc[t][c] = __builtin_amdgcn_mfma_f32_16x16x32_bf16(al[t], bh[c], acc[t][c], 0, 0, 0);
                    acc[t][c] = __builtin_amdgcn_mfma_f32_16x16x32_bf16(ah[t], bl[c], acc[t][c], 0, 0, 0);
                }
        }
        #pragma unroll
        for (int t = 0; t < 4; ++t)
            #pragma unroll
            for (int r = 0; r < 4; ++r) {
                int grow = row0 + t * 16 + quad * 4 + r;
                if (grow < N) {
                    int c0 = (wid * 2 + 0) * 16 + n16;
                    int c1 = (wid * 2 + 1) * 16 + n16;
                    if (mat == 0) {
                        Q16[(size_t)grow * 128 + c0] = (unsigned short)f2bf(acc[t][0][r] * QSCALE);
                        Q16[(size_t)grow * 128 + c1] = (unsigned short)f2bf(acc[t][1][r] * QSCALE);
                    } else {
                        size_t base = (size_t)grow * 256 + (mat - 1);  // K at +0, V at +1
                        KV16[base + 2 * c0] = (unsigned short)f2bf(acc[t][0][r]);
                        KV16[base + 2 * c1] = (unsigned short)f2bf(acc[t][1][r]);
                    }
                }
            }
    }
}

// ---------------- counting sort of edges by dst ----------------
__global__ __launch_bounds__(256) void hist_kernel(
    const int* __restrict__ ei, int* __restrict__ hist, int E)
{
    int e = blockIdx.x * blockDim.x + threadIdx.x;
    if (e < E) atomicAdd(&hist[ei[E + e]], 1);
}

#define SCAN_TPB 256
#define SCAN_EPT 4   // 1024 elements per scan block -> nb = ceil(N/1024) <= 64 for N <= 65536

__global__ __launch_bounds__(SCAN_TPB) void scan_partial(
    const int* __restrict__ hist, int* __restrict__ offs,
    int* __restrict__ blockSums, int N)
{
    __shared__ int sdata[SCAN_TPB];
    int b = blockIdx.x;
    int t = threadIdx.x;
    int base = b * SCAN_TPB * SCAN_EPT + t * SCAN_EPT;
    int v[SCAN_EPT];
    int tot = 0;
    #pragma unroll
    for (int j = 0; j < SCAN_EPT; ++j) {
        int idx = base + j;
        v[j] = (idx < N) ? hist[idx] : 0;
        tot += v[j];
    }
    sdata[t] = tot;
    __syncthreads();
    for (int off = 1; off < SCAN_TPB; off <<= 1) {
        int xv = (t >= off) ? sdata[t - off] : 0;
        __syncthreads();
        sdata[t] += xv;
        __syncthreads();
    }
    int run = sdata[t] - tot;
    #pragma unroll
    for (int j = 0; j < SCAN_EPT; ++j) {
        int idx = base + j;
        if (idx < N) offs[idx] = run;
        run += v[j];
    }
    if (t == SCAN_TPB - 1) blockSums[b] = sdata[t];
}

// adds block prefix; each block wave-scans the <=64 blockSums locally
// (fuses old scan_blocksums kernel). Writes offs (scatter working copy)
// and starts (kept).
__global__ __launch_bounds__(256) void scan_add(
    int* __restrict__ offs, int* __restrict__ starts,
    const int* __restrict__ blockSums, int N, int nb)
{
    __shared__ int bs[64];
    int t = threadIdx.x;
    if (t < 64) {
        int v = (t < nb) ? blockSums[t] : 0;
        #pragma unroll
        for (int off = 1; off < 64; off <<= 1) {
            int u = __shfl_up(v, off);
            if (t >= off) v += u;
        }
        bs[t] = v;   // inclusive scan
    }
    __syncthreads();
    int idx = blockIdx.x * blockDim.x + threadIdx.x;
    if (idx < N) {
        int blk = idx >> 10;
        int pref = (blk == 0) ? 0 : bs[blk - 1];
        int vv = offs[idx] + pref;
        offs[idx] = vv;
        starts[idx] = vv;
    }
}

// scatter: offs[d] consumed (becomes END offset after all increments)
__global__ __launch_bounds__(256) void scatter_kernel(
    const int* __restrict__ ei, int* __restrict__ offs,
    int* __restrict__ ssrc, int E)
{
    int e = blockIdx.x * blockDim.x + threadIdx.x;
    if (e < E) {
        int d = ei[E + e];
        int pos = atomicAdd(&offs[d], 1);
        ssrc[pos] = ei[e];
    }
}

// ---------------- per-node attention aggregation (no atomics) ----------------
// R7 layout: one wave per dst node; 4 edge slots (lane>>4) x 16 sublanes
// (lane&15) x 8 elements each; one 4-step swizzle allreduce serves 4 edges.
// R8: 1-deep software pipeline -- next batch's ssrc + KV loads are issued
// before computing the current batch (wave-uniform guard: i,end identical
// across the wave, so no divergence and no phantom prefetch traffic).
__global__ __launch_bounds__(256) void node_agg(
    const int* __restrict__ ssrc,
    const int* __restrict__ starts,
    const int* __restrict__ endoffs,
    const unsigned short* __restrict__ Q16,
    const unsigned short* __restrict__ KV16,
    float* __restrict__ agg, int N)
{
    int node = blockIdx.x * 4 + (threadIdx.x >> 6);
    if (node >= N) return;
    int lane = threadIdx.x & 63;
    int eg   = lane >> 4;        // edge slot 0..3
    int sl   = lane & 15;        // element group: elements sl*8 .. sl*8+7
    int start = starts[node];
    int end   = endoffs[node];

    if (start >= end) {          // degree-0 node: zero output, avoid ssrc[-1]
        if (eg == 0) {
            *((float4*)(agg + (size_t)node * 128 + sl * 8))     = make_float4(0.f, 0.f, 0.f, 0.f);
            *((float4*)(agg + (size_t)node * 128 + sl * 8 + 4)) = make_float4(0.f, 0.f, 0.f, 0.f);
        }
        return;
    }

    // q: one 16B bf16x8 load, unpacked once
    bfrag qv = *((const bfrag*)(Q16 + (size_t)node * 128 + sl * 8));
    float q0x = bf2f(qv[0]), q0y = bf2f(qv[1]), q0z = bf2f(qv[2]), q0w = bf2f(qv[3]);
    float q1x = bf2f(qv[4]), q1y = bf2f(qv[5]), q1z = bf2f(qv[6]), q1w = bf2f(qv[7]);

    float a0 = 0.f, a1 = 0.f, a2 = 0.f, a3 = 0.f;
    float a4 = 0.f, a5 = 0.f, a6 = 0.f, a7 = 0.f;

    const unsigned short* kvbase = KV16 + sl * 16;   // + s*256 per edge

    // prologue: load batch 0
    int i = start;
    {
        int i0 = i + eg;     i0 = (i0 < end) ? i0 : (end - 1);
        int i1 = i + 4 + eg; i1 = (i1 < end) ? i1 : (end - 1);
        // fallthrough into loop with these
        int s0 = ssrc[i0];
        int s1 = ssrc[i1];
        const unsigned short* kp0 = kvbase + ((size_t)s0 << 8);
        const unsigned short* kp1 = kvbase + ((size_t)s1 << 8);
        uint4 wa0 = *((const uint4*)kp0);
        uint4 wa1 = *((const uint4*)(kp0 + 8));
        uint4 wb0 = *((const uint4*)kp1);
        uint4 wb1 = *((const uint4*)(kp1 + 8));

        for (;;) {
            bool more = (i + 8) < end;          // wave-uniform
            uint4 na0, na1, nb0, nb1;
            if (more) {                          // prefetch next batch
                int j0 = i + 8 + eg;  j0 = (j0 < end) ? j0 : (end - 1);
                int j1 = i + 12 + eg; j1 = (j1 < end) ? j1 : (end - 1);
                int t0 = ssrc[j0];
                int t1 = ssrc[j1];
                const unsigned short* np0 = kvbase + ((size_t)t0 << 8);
                const unsigned short* np1 = kvbase + ((size_t)t1 << 8);
                na0 = *((const uint4*)np0);
                na1 = *((const uint4*)(np0 + 8));
                nb0 = *((const uint4*)np1);
                nb1 = *((const uint4*)(np1 + 8));
            }

            int ok0 = ((i + eg) < end);
            int ok1 = ((i + 4 + eg) < end);

            // dot products (K in low ushort of each dword)
            float p0, p1;
            p0 = q0x * klo(wa0.x);
            p0 = fmaf(q0y, klo(wa0.y), p0);
            p0 = fmaf(q0z, klo(wa0.z), p0);
            p0 = fmaf(q0w, klo(wa0.w), p0);
            p0 = fmaf(q1x, klo(wa1.x), p0);
            p0 = fmaf(q1y, klo(wa1.y), p0);
            p0 = fmaf(q1z, klo(wa1.z), p0);
            p0 = fmaf(q1w, klo(wa1.w), p0);
            p1 = q0x * klo(wb0.x);
            p1 = fmaf(q0y, klo(wb0.y), p1);
            p1 = fmaf(q0z, klo(wb0.z), p1);
            p1 = fmaf(q0w, klo(wb0.w), p1);
            p1 = fmaf(q1x, klo(wb1.x), p1);
            p1 = fmaf(q1y, klo(wb1.y), p1);
            p1 = fmaf(q1z, klo(wb1.z), p1);
            p1 = fmaf(q1w, klo(wb1.w), p1);

            // 4-step allreduce within each 16-lane group (4 edges at once)
            p0 += SWZ(p0, 0x041F); p1 += SWZ(p1, 0x041F);
            p0 += SWZ(p0, 0x081F); p1 += SWZ(p1, 0x081F);
            p0 += SWZ(p0, 0x101F); p1 += SWZ(p1, 0x101F);
            p0 += SWZ(p0, 0x201F); p1 += SWZ(p1, 0x201F);

            // sigmoid(q.k/sqrt(D)): Q pre-scaled negative -> c = 1/(1+exp(p))
            float c0 = __builtin_amdgcn_rcpf(1.f + __expf(p0));
            float c1 = __builtin_amdgcn_rcpf(1.f + __expf(p1));
            if (!ok0) c0 = 0.f;
            if (!ok1) c1 = 0.f;

            // accumulate c*V (V in high ushort of each dword)
            a0 = fmaf(c0, vhi(wa0.x), a0); a0 = fmaf(c1, vhi(wb0.x), a0);
            a1 = fmaf(c0, vhi(wa0.y), a1); a1 = fmaf(c1, vhi(wb0.y), a1);
            a2 = fmaf(c0, vhi(wa0.z), a2); a2 = fmaf(c1, vhi(wb0.z), a2);
            a3 = fmaf(c0, vhi(wa0.w), a3); a3 = fmaf(c1, vhi(wb0.w), a3);
            a4 = fmaf(c0, vhi(wa1.x), a4); a4 = fmaf(c1, vhi(wb1.x), a4);
            a5 = fmaf(c0, vhi(wa1.y), a5); a5 = fmaf(c1, vhi(wb1.y), a5);
            a6 = fmaf(c0, vhi(wa1.z), a6); a6 = fmaf(c1, vhi(wb1.z), a6);
            a7 = fmaf(c0, vhi(wa1.w), a7); a7 = fmaf(c1, vhi(wb1.w), a7);

            if (!more) break;
            wa0 = na0; wa1 = na1; wb0 = nb0; wb1 = nb1;
            i += 8;
        }
    }

    // combine the 4 edge-slot groups: xor16 (swizzle) + xor32 (shfl)
    a0 += SWZ(a0, 0x401F); a1 += SWZ(a1, 0x401F);
    a2 += SWZ(a2, 0x401F); a3 += SWZ(a3, 0x401F);
    a4 += SWZ(a4, 0x401F); a5 += SWZ(a5, 0x401F);
    a6 += SWZ(a6, 0x401F); a7 += SWZ(a7, 0x401F);
    a0 += __shfl_xor(a0, 32); a1 += __shfl_xor(a1, 32);
    a2 += __shfl_xor(a2, 32); a3 += __shfl_xor(a3, 32);
    a4 += __shfl_xor(a4, 32); a5 += __shfl_xor(a5, 32);
    a6 += __shfl_xor(a6, 32); a7 += __shfl_xor(a7, 32);

    if (eg == 0) {
        *((float4*)(agg + (size_t)node * 128 + sl * 8))     = make_float4(a0, a1, a2, a3);
        *((float4*)(agg + (size_t)node * 128 + sl * 8 + 4)) = make_float4(a4, a5, a6, a7);
    }
}

// ------- output GEMM (split-bf16 MFMA) + bias + residual + LayerNorm -------
__global__ __launch_bounds__(256) void out_ln_mfma(
    const float* __restrict__ agg,
    const short* __restrict__ whi, const short* __restrict__ wlo,  // Wo = mat 3
    const float* __restrict__ bo, const float* __restrict__ x,
    const float* __restrict__ gamma, const float* __restrict__ beta,
    float* __restrict__ out, int N)
{
    __shared__ __align__(16) char smem[64 * 136 * 2 * 2];   // 69632 B
    short (*xs_hi)[136] = (short(*)[136])smem;
    short (*xs_lo)[136] = (short(*)[136])(smem + 64 * 136 * 2);
    float (*hs)[132]    = (float(*)[132])smem;               // reused post-GEMM

    const int tid = threadIdx.x;
    const int row0 = blockIdx.x * BM;

    #pragma unroll
    for (int i = 0; i < 8; ++i) {
        int idx = tid + 256 * i;
        int r = idx >> 5;
        int c4 = idx & 31;
        int gr = row0 + r;
        float4 val = make_float4(0.f, 0.f, 0.f, 0.f);
        if (gr < N) val = ((const float4*)(agg + (size_t)gr * 128))[c4];
        short4 h, l;
        h.x = f2bf(val.x); l.x = f2bf(val.x - bf2f(h.x));
        h.y = f2bf(val.y); l.y = f2bf(val.y - bf2f(h.y));
        h.z = f2bf(val.z); l.z = f2bf(val.z - bf2f(h.z));
        h.w = f2bf(val.w); l.w = f2bf(val.w - bf2f(h.w));
        *((short4*)&xs_hi[r][c4 * 4]) = h;
        *((short4*)&xs_lo[r][c4 * 4]) = l;
    }
    __syncthreads();

    const int wid  = tid >> 6;
    const int lane = tid & 63;
    const int n16  = lane & 15;
    const int quad = lane >> 4;
    const short* __restrict__ WH = whi + 3 * 16384;
    const short* __restrict__ WL = wlo + 3 * 16384;

    const f32x4 zero = {0.f, 0.f, 0.f, 0.f};
    f32x4 acc[4][2];
    #pragma unroll
    for (int t = 0; t < 4; ++t) { acc[t][0] = zero; acc[t][1] = zero; }

    #pragma unroll
    for (int kc = 0; kc < 4; ++kc) {
        int k0 = kc * 32 + quad * 8;
        bfrag ah[4], al[4], bh[2], bl[2];
        #pragma unroll
        for (int t = 0; t < 4; ++t) {
            ah[t] = *((const bfrag*)&xs_hi[t * 16 + n16][k0]);
            al[t] = *((const bfrag*)&xs_lo[t * 16 + n16][k0]);
        }
        #pragma unroll
        for (int c = 0; c < 2; ++c) {
            int wr = (wid * 2 + c) * 16 + n16;
            bh[c] = *((const bfrag*)(WH + wr * 128 + k0));
            bl[c] = *((const bfrag*)(WL + wr * 128 + k0));
        }
        #pragma unroll
        for (int t = 0; t < 4; ++t)
            #pragma unroll
            for (int c = 0; c < 2; ++c) {
                acc[t][c] = __builtin_amdgcn_mfma_f32_16x16x32_bf16(ah[t], bh[c], acc[t][c], 0, 0, 0);
                acc[t][c] = __builtin_amdgcn_mfma_f32_16x16x32_bf16(al[t], bh[c], acc[t][c], 0, 0, 0);
                acc[t][c] = __builtin_amdgcn_mfma_f32_16x16x32_bf16(ah[t], bl[c], acc[t][c], 0, 0, 0);
            }
    }
    __syncthreads();   // all xs reads done before hs overwrite

    #pragma unroll
    for (int t = 0; t < 4; ++t)
        #pragma unroll
        for (int r = 0; r < 4; ++r) {
            hs[t * 16 + quad * 4 + r][(wid * 2 + 0) * 16 + n16] = acc[t][0][r];
            hs[t * 16 + quad * 4 + r][(wid * 2 + 1) * 16 + n16] = acc[t][1][r];
        }
    __syncthreads();

    {
        int r = tid >> 2;
        int qd = tid & 3;
        int gr = row0 + r;
        float sum = 0.f, sq = 0.f;
        #pragma unroll
        for (int c = 0; c < 32; c += 4) {
            float4 g4 = *((float4*)&hs[r][qd * 32 + c]);
            float4 b4 = *((const float4*)(bo + qd * 32 + c));
            float4 x4 = make_float4(0.f, 0.f, 0.f, 0.f);
            if (gr < N) x4 = *((const float4*)(x + (size_t)gr * 128 + qd * 32 + c));
            float4 h = make_float4(g4.x + b4.x + x4.x, g4.y + b4.y + x4.y,
                                   g4.z + b4.z + x4.z, g4.w + b4.w + x4.w);
            *((float4*)&hs[r][qd * 32 + c]) = h;
            sum += h.x + h.y + h.z + h.w;
            sq += h.x * h.x + h.y * h.y + h.z * h.z + h.w * h.w;
        }
        sum += __shfl_xor(sum, 1); sum += __shfl_xor(sum, 2);
        sq  += __shfl_xor(sq, 1);  sq  += __shfl_xor(sq, 2);
        float mu = sum * (1.f / 128.f);
        float var = sq * (1.f / 128.f) - mu * mu;
        float rs = rsqrtf(var + 1e-5f);
        if (gr < N) {
            #pragma unroll
            for (int c = 0; c < 32; c += 4) {
                float4 h = *((float4*)&hs[r][qd * 32 + c]);
                float4 g = *((const float4*)(gamma + qd * 32 + c));
                float4 b = *((const float4*)(beta + qd * 32 + c));
                float4 o = make_float4((h.x - mu) * rs * g.x + b.x,
                                       (h.y - mu) * rs * g.y + b.y,
                                       (h.z - mu) * rs * g.z + b.z,
                                       (h.w - mu) * rs * g.w + b.w);
                *((float4*)(out + (size_t)gr * 128 + qd * 32 + c)) = o;
            }
        }
    }
}

extern "C" void kernel_launch(void* const* d_in, const int* in_sizes, int n_in,
                              void* d_out, int out_size, void* d_ws, size_t ws_size,
                              hipStream_t stream) {
    const float* x     = (const float*)d_in[0];
    const int*   ei    = (const int*)d_in[1];
    const float* Wq    = (const float*)d_in[2];
    const float* Wk    = (const float*)d_in[3];
    const float* Wv    = (const float*)d_in[4];
    const float* Wo    = (const float*)d_in[5];
    const float* bo    = (const float*)d_in[6];
    const float* gamma = (const float*)d_in[7];
    const float* beta  = (const float*)d_in[8];
    const int N = in_sizes[0] / 128;
    const int E = in_sizes[1] / 2;
    const size_t ND = (size_t)N * 128;

    // workspace: Q16 bf16 12.8MB + KV16 interleaved bf16 25.6MB + agg 25.6MB
    //            + hist/offs/starts + blockSums + ssrc + whi/wlo
    unsigned short* Q16  = (unsigned short*)d_ws;
    unsigned short* KV16 = Q16 + ND;                     // 2*ND ushorts
    float* agg = (float*)(KV16 + 2 * ND);
    int* hist      = (int*)(agg + ND);
    int* offs      = hist + N;
    int* starts    = offs + N;
    int* blockSums = starts + N;       // 256 ints
    int* ssrc      = blockSums + 256;  // E ints
    short* whi     = (short*)(ssrc + E);        // 4*16384 shorts
    short* wlo     = whi + 4 * 16384;

    const int gzp = ((N > 65536 ? N : 65536) + 255) / 256;
    zero_prep<<<gzp, 256, 0, stream>>>(Wq, Wk, Wv, Wo, whi, wlo, hist, N);

    hist_kernel<<<(E + 255) / 256, 256, 0, stream>>>(ei, hist, E);
    const int nScanBlocks = (N + SCAN_TPB * SCAN_EPT - 1) / (SCAN_TPB * SCAN_EPT);
    scan_partial<<<nScanBlocks, SCAN_TPB, 0, stream>>>(hist, offs, blockSums, N);
    scan_add<<<(N + 255) / 256, 256, 0, stream>>>(offs, starts, blockSums, N, nScanBlocks);
    scatter_kernel<<<(E + 255) / 256, 256, 0, stream>>>(ei, offs, ssrc, E);

    const int gq = (N + BM - 1) / BM;
    qkv_mfma<<<gq, 256, 0, stream>>>(x, whi, wlo, Q16, KV16, N);

    node_agg<<<(N + 3) / 4, 256, 0, stream>>>(ssrc, starts, offs, Q16, KV16, agg, N);

    out_ln_mfma<<<gq, 256, 0, stream>>>(agg, whi, wlo, bo, x, gamma, beta,
                                        (float*)d_out, N);
}